// Round 12
// baseline (589.747 us; speedup 1.0000x reference)
//
#include <hip/hip_runtime.h>
#include <hip/hip_bf16.h>
#include <math.h>

#define NTOK 1024
#define DDIM 768
#define MDIM 3072
#define GN 4
#define EN 8
#define NEXP 32
#define NPAIR 8192
#define EPSW 1e-6f
#define MAXRB 64   // max 256-row blocks: 32 full + <=32 partials

typedef __attribute__((ext_vector_type(4))) float f32x4;
typedef __attribute__((ext_vector_type(4))) int   i32x4;
typedef __attribute__((ext_vector_type(4))) unsigned short u16x4;
typedef __attribute__((ext_vector_type(8))) __bf16 bf16x8;

__device__ __forceinline__ unsigned short f2bf(float f) {
  unsigned u = __builtin_bit_cast(unsigned, f);
  u += 0x7FFFu + ((u >> 16) & 1u);
  return (unsigned short)(u >> 16);
}

__device__ __forceinline__ void gld_lds16(const void* g, void* l) {
  __builtin_amdgcn_global_load_lds(
      (const __attribute__((address_space(1))) void*)g,
      (__attribute__((address_space(3))) void*)l, 16, 0, 0);
}

// ---------------------------------------------------------------------------
// Init + zero-y + x->bf16.
// ---------------------------------------------------------------------------
__global__ void init_kernel(int* __restrict__ p) { p[threadIdx.x] = 0; }

__global__ __launch_bounds__(256) void zero_y(float* __restrict__ y) {
  ((f32x4*)y)[blockIdx.x * 256 + threadIdx.x] = (f32x4){0.f, 0.f, 0.f, 0.f};
}

__global__ __launch_bounds__(256) void x2bf(const float* __restrict__ x,
                                            unsigned short* __restrict__ xb) {
  const int i = (blockIdx.x * 256 + threadIdx.x) * 16;
#pragma unroll
  for (int j = 0; j < 4; ++j) {
    const f32x4 v = *(const f32x4*)(x + i + j * 4);
    u16x4 p = { f2bf(v.x), f2bf(v.y), f2bf(v.z), f2bf(v.w) };
    *(u16x4*)(xb + i + j * 4) = p;
  }
}

// ---------------------------------------------------------------------------
// Kernel 1: gating (proven correct).
// ---------------------------------------------------------------------------
__global__ __launch_bounds__(256) void gating_kernel(
    const float* __restrict__ x, const float* __restrict__ Wg,
    const float* __restrict__ bg, const float* __restrict__ We,
    const float* __restrict__ be, int* __restrict__ counts,
    int* __restrict__ pair_e, float* __restrict__ pair_w)
{
  __shared__ float xr[DDIM];
  __shared__ float logits[36];
  const int n = blockIdx.x;
  const int tid = threadIdx.x;
  const float* xp = x + (size_t)n * DDIM;
  for (int d = tid; d < DDIM; d += 256) xr[d] = xp[d];
  __syncthreads();

  const int w = tid >> 6, lane = tid & 63;
  for (int j = 0; j < 9; ++j) {
    const int o = w + 4 * j;  // 0..35
    float s = 0.f;
    if (o < 4) {
      for (int d = lane; d < DDIM; d += 64) s += xr[d] * Wg[d * GN + o];
    } else {
      const int g = (o - 4) >> 3, e = (o - 4) & 7;
      const float* wp = We + (size_t)g * DDIM * EN + e;
      for (int d = lane; d < DDIM; d += 64) s += xr[d] * wp[d * EN];
    }
    for (int off = 32; off; off >>= 1) s += __shfl_xor(s, off);
    if (lane == 0) logits[o] = s + ((o < 4) ? bg[o] : be[o - 4]);
  }
  __syncthreads();

  if (tid == 0) {
    float gl[4];
    for (int i = 0; i < 4; ++i) gl[i] = logits[i];
    int i0 = 0;
    for (int i = 1; i < 4; ++i) if (gl[i] > gl[i0]) i0 = i;
    int i1 = -1;
    for (int i = 0; i < 4; ++i) {
      if (i == i0) continue;
      if (i1 < 0 || gl[i] > gl[i1]) i1 = i;
    }
    const float m = gl[i0];
    const float e1 = expf(gl[i1] - m);
    const float s2 = 1.f + e1;
    float gv[2] = { 1.f / s2, e1 / s2 };
    int gi[2] = { i0, i1 };
    for (int r = 0; r < 2; ++r) if (gv[r] < EPSW) gv[r] = 0.f;

    for (int r = 0; r < 2; ++r) {
      const int g = gi[r];
      float el[8];
      for (int e = 0; e < 8; ++e) el[e] = logits[4 + g * 8 + e];
      int sel[4];
      for (int q = 0; q < 4; ++q) {
        int best = -1;
        for (int e = 0; e < 8; ++e) {
          bool used = false;
          for (int p = 0; p < q; ++p) if (sel[p] == e) used = true;
          if (used) continue;
          if (best < 0 || el[e] > el[best]) best = e;
        }
        sel[q] = best;
      }
      const float mm = el[sel[0]];
      float ex[4]; float ss = 0.f;
      for (int q = 0; q < 4; ++q) { ex[q] = expf(el[sel[q]] - mm); ss += ex[q]; }
      for (int q = 0; q < 4; ++q) {
        float ew = ex[q] / ss;
        if (ew < EPSW) ew = 0.f;
        const int gbl = g * 8 + sel[q];
        const int j = r * 4 + q;
        pair_e[n * 8 + j] = gbl;
        pair_w[n * 8 + j] = gv[r] * ew;
        atomicAdd(&counts[gbl], 1);
      }
    }
  }
}

// ---------------------------------------------------------------------------
// Kernel 2: scan + 256-row-block lookup table (rb -> expert, local by).
// ---------------------------------------------------------------------------
__global__ void scan_kernel(const int* __restrict__ counts, int* __restrict__ offsets,
                            int* __restrict__ rb_ge, int* __restrict__ rb_by,
                            int* __restrict__ nrb)
{
  if (threadIdx.x == 0) {
    int a = 0, n = 0;
    for (int e = 0; e < NEXP; ++e) {
      offsets[e] = a;
      const int c = counts[e];
      a += c;
      for (int b = 0; b * 256 < c; ++b) { rb_ge[n] = e; rb_by[n] = b; ++n; }
    }
    *nrb = n;
  }
}

// ---------------------------------------------------------------------------
// Kernel 3: slot bookkeeping (FC1 gathers token rows directly from xb).
// ---------------------------------------------------------------------------
__global__ __launch_bounds__(256) void scatter_kernel(
    const int* __restrict__ pair_e, const float* __restrict__ pair_w,
    const int* __restrict__ offsets, int* __restrict__ cursor,
    int* __restrict__ slot_tok, float* __restrict__ slot_w)
{
  const int idx = blockIdx.x * 256 + threadIdx.x;
  if (idx < NPAIR) {
    const int e = pair_e[idx];
    const int s = offsets[e] + atomicAdd(&cursor[e], 1);
    slot_tok[s] = idx >> 3;
    slot_w[s] = pair_w[idx];
  }
}

// ---------------------------------------------------------------------------
// Kernel 4: BM=256 x BN=64 fused GEMM, fp32 weights direct.
// 256 threads, 4 waves; wave-tile 64x64 (acc = 64 VGPR). BK=32.
// A (bf16, k-contig) staged via global_load_lds: pre-swizzled SOURCE,
// linear LDS dest, ZERO staging registers (round-5-proven pattern).
// B (fp32, n-contig) reg-staged: 8 coalesced dwords/thread -> f2bf ->
// swizzled [n][k] LDS write.
// Fence correctness WITHOUT counted vmcnt: per step, gld_lds A(t+1) is
// issued BEFORE B(t+1)'s register loads (pinned by sched_barrier(0));
// vmcnt retires in issue order, so the compiler-inserted waits on B(t)'s
// registers at CVTW(t) also guarantee A(t)'s gld_lds have completed.
// One raw barrier per K-step; ISSUE_A(t+1) placed after barrier(t) so
// its target buffer is provably no longer being read by any wave.
// GATHER=1: A rows = xb[slot_tok[slot]] (FC1).  GATHER=0: A rows = H (FC2).
// EPI 0: H = bf16(gelu(C + b1)).  EPI 1: atomicAdd y[tok] += slot_w*(C+b2).
// ---------------------------------------------------------------------------
template<int K, int NLD, int EPI, int GATHER, int KS>
__global__ __launch_bounds__(256, 3) void moe_gemm_bw(
    const unsigned short* __restrict__ Abase, const float* __restrict__ W,
    const float* __restrict__ bias, const int* __restrict__ counts,
    const int* __restrict__ offsets, const float* __restrict__ slot_w,
    const int* __restrict__ slot_tok, const int* __restrict__ rb_ge,
    const int* __restrict__ rb_by, const int* __restrict__ nrb,
    unsigned short* __restrict__ Hout, float* __restrict__ Yout)
{
  constexpr int KC = K / KS;        // K-chunk
  constexpr int NT = KC / 32;       // K-steps: FC1 24, FC2 48; even
  constexpr int ABY = 16384;        // A tile: 256 rows x 64 B
  constexpr int BUFB = ABY + 4096;  // + B tile: 64 x 64 B

  const int rb = blockIdx.x;
  if (rb >= *nrb) return;
  const int ge = rb_ge[rb];
  const int by = rb_by[rb];
  const int cnt = counts[ge];
  const int off = offsets[ge];
  const int nb = blockIdx.y;
  const int ks = (KS > 1) ? blockIdx.z : 0;
  const int kbase = ks * KC;
  const int tid = threadIdx.x;

  __shared__ __align__(16) unsigned char lds[2 * BUFB];

  // ---- A gld sources: 4 slots q = tid + 256*i; row m = q>>2, chunk c = q&3.
  // Source chunk pre-swizzled (c ^ s(m)); LDS dest linear (slot*16).
  const unsigned short* asrc[4];
#pragma unroll
  for (int i = 0; i < 4; ++i) {
    const int q = tid + 256 * i;
    const int m = q >> 2, c = q & 3;
    const int sc = c ^ ((m ^ (m >> 2)) & 3);
    int gr = by * 256 + m; if (gr >= cnt) gr = cnt - 1;
    const int row = GATHER ? slot_tok[off + gr] : (off + gr);
    asrc[i] = Abase + (size_t)row * K + kbase + sc * 8;
  }

  // ---- B staging: thread = (kq 0..7, ln 0..31); 8 dwords per K-step.
  const int kq = tid >> 5, ln = tid & 31;
  const float* bp = W + (size_t)ge * K * NLD + (size_t)(kbase + kq * 4) * NLD
                      + nb * 64 + ln;
  int bwr[2];
#pragma unroll
  for (int ii = 0; ii < 2; ++ii) {
    const int n = ln + 32 * ii;
    const int s = (n ^ (n >> 2)) & 3;
    bwr[ii] = ABY + n * 64 + (((kq >> 1) ^ s) * 16) + ((kq & 1) * 8);
  }

  // ---- fragment geometry: wave w covers rows w*64..w*64+63, all 64 cols.
  const int w = tid >> 6, lane = tid & 63;
  const int l15 = lane & 15, l4 = lane >> 4;
  int aoff[4], boff[4];
#pragma unroll
  for (int mf = 0; mf < 4; ++mf) {
    const int m = w * 64 + mf * 16 + l15;
    aoff[mf] = m * 64 + ((l4 ^ ((m ^ (m >> 2)) & 3)) * 16);
  }
#pragma unroll
  for (int nf = 0; nf < 4; ++nf) {
    const int n = nf * 16 + l15;
    boff[nf] = ABY + n * 64 + ((l4 ^ ((n ^ (n >> 2)) & 3)) * 16);
  }

  f32x4 acc[4][4];
#pragma unroll
  for (int mf = 0; mf < 4; ++mf)
#pragma unroll
    for (int nf = 0; nf < 4; ++nf)
      acc[mf][nf] = (f32x4){0.f, 0.f, 0.f, 0.f};

  float bA[8], bB[8];

#define ISSUE_A(T, BASE) { _Pragma("unroll") \
    for (int i = 0; i < 4; ++i) \
      gld_lds16(asrc[i] + (T) * 32, (BASE) + (tid + 256 * i) * 16); }
#define LOADB(T, BS) { _Pragma("unroll") \
    for (int ii = 0; ii < 2; ++ii) { _Pragma("unroll") \
      for (int jj = 0; jj < 4; ++jj) \
        BS[ii * 4 + jj] = bp[(size_t)((T) * 32 + jj) * NLD + 32 * ii]; } }
#define CVTW(BS, BASE) { _Pragma("unroll") \
    for (int ii = 0; ii < 2; ++ii) { \
      u16x4 p = { f2bf(BS[ii*4+0]), f2bf(BS[ii*4+1]), f2bf(BS[ii*4+2]), f2bf(BS[ii*4+3]) }; \
      *(u16x4*)((BASE) + bwr[ii]) = p; } }
#define COMPUTE(BASE) { bf16x8 afr[4], bfr[4]; _Pragma("unroll") \
    for (int mf = 0; mf < 4; ++mf) \
      afr[mf] = __builtin_bit_cast(bf16x8, *(const i32x4*)((BASE) + aoff[mf])); \
    _Pragma("unroll") \
    for (int nf = 0; nf < 4; ++nf) \
      bfr[nf] = __builtin_bit_cast(bf16x8, *(const i32x4*)((BASE) + boff[nf])); \
    _Pragma("unroll") \
    for (int mf = 0; mf < 4; ++mf) { _Pragma("unroll") \
      for (int nf = 0; nf < 4; ++nf) \
        acc[mf][nf] = __builtin_amdgcn_mfma_f32_16x16x32_bf16( \
            afr[mf], bfr[nf], acc[mf][nf], 0, 0, 0); } }
// One K-step. Order matters: CVTW(t) (compiler waits on B(t) regs, which
// fences A(t) gld_lds by issue order) -> lgkm drain -> barrier -> issue
// A(t+1) into the buffer all waves just vacated -> pin order -> B(t+1)
// reg loads -> MFMA on tile t (hides the new loads' latency).
#define STEP(T, CB, IB, BASE, OBASE) { \
    CVTW(CB, BASE); \
    asm volatile("s_waitcnt lgkmcnt(0)" ::: "memory"); \
    __builtin_amdgcn_s_barrier(); \
    asm volatile("" ::: "memory"); \
    if ((T) + 1 < NT) { \
      ISSUE_A((T) + 1, OBASE); \
      __builtin_amdgcn_sched_barrier(0); \
      LOADB((T) + 1, IB); \
    } \
    COMPUTE(BASE); \
  }

  // ---- prologue: tile 0 -> buf0 / set A
  ISSUE_A(0, lds);
  __builtin_amdgcn_sched_barrier(0);
  LOADB(0, bA);

  for (int t = 0; t < NT; t += 2) {
    STEP(t,     bA, bB, lds,        lds + BUFB);
    STEP(t + 1, bB, bA, lds + BUFB, lds);
  }
#undef ISSUE_A
#undef LOADB
#undef CVTW
#undef COMPUTE
#undef STEP

  // ---- epilogue. C/D layout: col = lane&15, row = (lane>>4)*4 + j
#pragma unroll
  for (int mf = 0; mf < 4; ++mf) {
    const int rb2 = by * 256 + w * 64 + mf * 16 + l4 * 4;
    if constexpr (EPI == 0) {
#pragma unroll
      for (int nf = 0; nf < 4; ++nf) {
        const int col = nb * 64 + nf * 16 + l15;
        const float bv = bias[(size_t)ge * NLD + col];
#pragma unroll
        for (int j = 0; j < 4; ++j) {
          const int r = rb2 + j;
          if (r < cnt) {
            const float v = acc[mf][nf][j] + bv;
            const float gl = 0.5f * v * (1.f + erff(v * 0.70710678118654752f));
            Hout[(size_t)(off + r) * NLD + col] = f2bf(gl);
          }
        }
      }
    } else {
#pragma unroll
      for (int j = 0; j < 4; ++j) {
        const int r = rb2 + j;
        if (r < cnt) {
          const int slot = off + r;
          const float sw = slot_w[slot];
          const int tok = slot_tok[slot];
#pragma unroll
          for (int nf = 0; nf < 4; ++nf) {
            const int col = nb * 64 + nf * 16 + l15;
            const float bv = (ks == 0) ? bias[(size_t)ge * NLD + col] : 0.f;
            atomicAdd(&Yout[(size_t)tok * DDIM + col], sw * (acc[mf][nf][j] + bv));
          }
        }
      }
    }
  }
}

// ---------------------------------------------------------------------------
// Workspace layout (bytes):
//   0    counts[32]     128  offsets[32]    256  cursor[32]   384 nrb
//   512  rb_ge[64]      896  rb_by[64]
//   2048 pair_e[8192]   34816 pair_w[8192]
//   67584 slot_tok[8192] 100352 slot_w[8192]
//   135168 xb[1024][768] bf16 (1.57 MB)
//   12715008 H[8192][3072] bf16 (50.3 MB)    (ws ~1.2 GB available)
// ---------------------------------------------------------------------------
extern "C" void kernel_launch(void* const* d_in, const int* in_sizes, int n_in,
                              void* d_out, int out_size, void* d_ws, size_t ws_size,
                              hipStream_t stream)
{
  const float* x  = (const float*)d_in[0];
  const float* Wg = (const float*)d_in[1];
  const float* bg = (const float*)d_in[2];
  const float* We = (const float*)d_in[3];
  const float* be = (const float*)d_in[4];
  const float* W1 = (const float*)d_in[5];
  const float* b1 = (const float*)d_in[6];
  const float* W2 = (const float*)d_in[7];
  const float* b2 = (const float*)d_in[8];
  float* y = (float*)d_out;

  char* ws = (char*)d_ws;
  int*   counts   = (int*)(ws + 0);
  int*   offsets  = (int*)(ws + 128);
  int*   cursor   = (int*)(ws + 256);
  int*   nrb      = (int*)(ws + 384);
  int*   rb_ge    = (int*)(ws + 512);
  int*   rb_by    = (int*)(ws + 896);
  int*   pair_e   = (int*)(ws + 2048);
  float* pair_w   = (float*)(ws + 34816);
  int*   slot_tok = (int*)(ws + 67584);
  float* slot_w   = (float*)(ws + 100352);
  unsigned short* xb = (unsigned short*)(ws + 135168);
  unsigned short* H  = (unsigned short*)(ws + 12715008);

  init_kernel<<<1, 256, 0, stream>>>((int*)ws);
  zero_y<<<NTOK * DDIM / 1024, 256, 0, stream>>>(y);
  x2bf<<<NTOK * DDIM / 4096, 256, 0, stream>>>(x, xb);
  gating_kernel<<<NTOK, 256, 0, stream>>>(x, Wg, bg, We, be, counts, pair_e, pair_w);
  scan_kernel<<<1, 64, 0, stream>>>(counts, offsets, rb_ge, rb_by, nrb);
  scatter_kernel<<<NPAIR / 256, 256, 0, stream>>>(pair_e, pair_w, offsets, cursor,
                                                  slot_tok, slot_w);

  // FC1: 64 row-blocks x 48 n-blocks; W1 fp32 direct; A gathered from xb.
  moe_gemm_bw<DDIM, MDIM, 0, 1, 1><<<dim3(MAXRB, MDIM / 64, 1), 256, 0, stream>>>(
      xb, W1, b1, counts, offsets, nullptr, slot_tok, rb_ge, rb_by, nrb, H, nullptr);
  // FC2: 64 row-blocks x 12 n-blocks x K-split 2; atomic into y.
  moe_gemm_bw<MDIM, DDIM, 1, 0, 2><<<dim3(MAXRB, DDIM / 64, 2), 256, 0, stream>>>(
      H, W2, b2, counts, offsets, slot_w, slot_tok, rb_ge, rb_by, nrb, nullptr, y);
}

// Round 13
// 562.148 us; speedup vs baseline: 1.0491x; 1.0491x over previous
//
#include <hip/hip_runtime.h>
#include <hip/hip_bf16.h>
#include <math.h>

#define NTOK 1024
#define DDIM 768
#define MDIM 3072
#define GN 4
#define EN 8
#define NEXP 32
#define NPAIR 8192
#define EPSW 1e-6f
#define MAXRB 96   // max 128-row blocks: 64 full + <=32 partials

typedef __attribute__((ext_vector_type(4))) float f32x4;
typedef __attribute__((ext_vector_type(4))) int   i32x4;
typedef __attribute__((ext_vector_type(4))) unsigned short u16x4;
typedef __attribute__((ext_vector_type(8))) __bf16 bf16x8;

__device__ __forceinline__ unsigned short f2bf(float f) {
  unsigned u = __builtin_bit_cast(unsigned, f);
  u += 0x7FFFu + ((u >> 16) & 1u);
  return (unsigned short)(u >> 16);
}

__device__ __forceinline__ unsigned cvt_pk_bf16(float lo, float hi) {
  unsigned r;
  asm volatile("v_cvt_pk_bf16_f32 %0, %1, %2" : "=v"(r) : "v"(lo), "v"(hi));
  return r;
}

__device__ __forceinline__ void gld_lds16(const void* g, void* l) {
  __builtin_amdgcn_global_load_lds(
      (const __attribute__((address_space(1))) void*)g,
      (__attribute__((address_space(3))) void*)l, 16, 0, 0);
}

// ---------------------------------------------------------------------------
// Init + zero-y + x->bf16.
// ---------------------------------------------------------------------------
__global__ void init_kernel(int* __restrict__ p) { p[threadIdx.x] = 0; }

__global__ __launch_bounds__(256) void zero_y(float* __restrict__ y) {
  ((f32x4*)y)[blockIdx.x * 256 + threadIdx.x] = (f32x4){0.f, 0.f, 0.f, 0.f};
}

__global__ __launch_bounds__(256) void x2bf(const float* __restrict__ x,
                                            unsigned short* __restrict__ xb) {
  const int i = (blockIdx.x * 256 + threadIdx.x) * 16;
#pragma unroll
  for (int j = 0; j < 4; ++j) {
    const f32x4 v = *(const f32x4*)(x + i + j * 4);
    u16x4 p = { f2bf(v.x), f2bf(v.y), f2bf(v.z), f2bf(v.w) };
    *(u16x4*)(xb + i + j * 4) = p;
  }
}

// ---------------------------------------------------------------------------
// Kernel 1: gating (proven correct).
// ---------------------------------------------------------------------------
__global__ __launch_bounds__(256) void gating_kernel(
    const float* __restrict__ x, const float* __restrict__ Wg,
    const float* __restrict__ bg, const float* __restrict__ We,
    const float* __restrict__ be, int* __restrict__ counts,
    int* __restrict__ pair_e, float* __restrict__ pair_w)
{
  __shared__ float xr[DDIM];
  __shared__ float logits[36];
  const int n = blockIdx.x;
  const int tid = threadIdx.x;
  const float* xp = x + (size_t)n * DDIM;
  for (int d = tid; d < DDIM; d += 256) xr[d] = xp[d];
  __syncthreads();

  const int w = tid >> 6, lane = tid & 63;
  for (int j = 0; j < 9; ++j) {
    const int o = w + 4 * j;  // 0..35
    float s = 0.f;
    if (o < 4) {
      for (int d = lane; d < DDIM; d += 64) s += xr[d] * Wg[d * GN + o];
    } else {
      const int g = (o - 4) >> 3, e = (o - 4) & 7;
      const float* wp = We + (size_t)g * DDIM * EN + e;
      for (int d = lane; d < DDIM; d += 64) s += xr[d] * wp[d * EN];
    }
    for (int off = 32; off; off >>= 1) s += __shfl_xor(s, off);
    if (lane == 0) logits[o] = s + ((o < 4) ? bg[o] : be[o - 4]);
  }
  __syncthreads();

  if (tid == 0) {
    float gl[4];
    for (int i = 0; i < 4; ++i) gl[i] = logits[i];
    int i0 = 0;
    for (int i = 1; i < 4; ++i) if (gl[i] > gl[i0]) i0 = i;
    int i1 = -1;
    for (int i = 0; i < 4; ++i) {
      if (i == i0) continue;
      if (i1 < 0 || gl[i] > gl[i1]) i1 = i;
    }
    const float m = gl[i0];
    const float e1 = expf(gl[i1] - m);
    const float s2 = 1.f + e1;
    float gv[2] = { 1.f / s2, e1 / s2 };
    int gi[2] = { i0, i1 };
    for (int r = 0; r < 2; ++r) if (gv[r] < EPSW) gv[r] = 0.f;

    for (int r = 0; r < 2; ++r) {
      const int g = gi[r];
      float el[8];
      for (int e = 0; e < 8; ++e) el[e] = logits[4 + g * 8 + e];
      int sel[4];
      for (int q = 0; q < 4; ++q) {
        int best = -1;
        for (int e = 0; e < 8; ++e) {
          bool used = false;
          for (int p = 0; p < q; ++p) if (sel[p] == e) used = true;
          if (used) continue;
          if (best < 0 || el[e] > el[best]) best = e;
        }
        sel[q] = best;
      }
      const float mm = el[sel[0]];
      float ex[4]; float ss = 0.f;
      for (int q = 0; q < 4; ++q) { ex[q] = expf(el[sel[q]] - mm); ss += ex[q]; }
      for (int q = 0; q < 4; ++q) {
        float ew = ex[q] / ss;
        if (ew < EPSW) ew = 0.f;
        const int gbl = g * 8 + sel[q];
        const int j = r * 4 + q;
        pair_e[n * 8 + j] = gbl;
        pair_w[n * 8 + j] = gv[r] * ew;
        atomicAdd(&counts[gbl], 1);
      }
    }
  }
}

// ---------------------------------------------------------------------------
// Kernel 2: scan + 128-row-block lookup table (rb -> expert, local by).
// ---------------------------------------------------------------------------
__global__ void scan_kernel(const int* __restrict__ counts, int* __restrict__ offsets,
                            int* __restrict__ rb_ge, int* __restrict__ rb_by,
                            int* __restrict__ nrb)
{
  if (threadIdx.x == 0) {
    int a = 0, n = 0;
    for (int e = 0; e < NEXP; ++e) {
      offsets[e] = a;
      const int c = counts[e];
      a += c;
      for (int b = 0; b * 128 < c; ++b) { rb_ge[n] = e; rb_by[n] = b; ++n; }
    }
    *nrb = n;
  }
}

// ---------------------------------------------------------------------------
// Kernel 3: slot bookkeeping (FC1 gathers token rows directly from xb).
// ---------------------------------------------------------------------------
__global__ __launch_bounds__(256) void scatter_kernel(
    const int* __restrict__ pair_e, const float* __restrict__ pair_w,
    const int* __restrict__ offsets, int* __restrict__ cursor,
    int* __restrict__ slot_tok, float* __restrict__ slot_w)
{
  const int idx = blockIdx.x * 256 + threadIdx.x;
  if (idx < NPAIR) {
    const int e = pair_e[idx];
    const int s = offsets[e] + atomicAdd(&cursor[e], 1);
    slot_tok[s] = idx >> 3;
    slot_w[s] = pair_w[idx];
  }
}

// ---------------------------------------------------------------------------
// Kernel 4: all-global_load_lds GEMM with LDS-side B transpose.
// C[rows x NLD] = A_seg[rows x K](bf16) * W[ge][K x NLD](fp32).
// BM=128, BN=128, BK=32, 4 waves, mfma 16x16x32 bf16.
// Per K-step, per thread: 6 global_load_lds x16B (A bf16 2, B fp32 4),
// ALL coalesced, ZERO staging registers (nothing can spill -> the only
// VMEM in flight is these 6 loads -> vmcnt(0) is exact and safe).
// Then a transpose-convert phase: 16 strided LDS fp32 reads (2-way banks,
// free) -> v_cvt_pk_bf16_f32 -> 8 swizzled u32 writes into bf16 [n][k].
// Schedule per step: vmcnt(0); barrier; issue tile t+1 (flies across the
// rest of the step); transpose tile t; lgkmcnt(0); barrier; MFMA tile t.
// GATHER=1: A rows = xb[slot_tok[slot]] (FC1).  GATHER=0: A rows = H (FC2).
// EPI 0: H = bf16(gelu(C + b1)).  EPI 1: atomicAdd y[tok] += slot_w*(C+b2).
// ---------------------------------------------------------------------------
template<int K, int NLD, int EPI, int GATHER, int KS>
__global__ __launch_bounds__(256, 2) void moe_gemm_gl(
    const unsigned short* __restrict__ Abase, const float* __restrict__ W,
    const float* __restrict__ bias, const int* __restrict__ counts,
    const int* __restrict__ offsets, const float* __restrict__ slot_w,
    const int* __restrict__ slot_tok, const int* __restrict__ rb_ge,
    const int* __restrict__ rb_by, const int* __restrict__ nrb,
    unsigned short* __restrict__ Hout, float* __restrict__ Yout)
{
  constexpr int KC = K / KS;        // K-chunk
  constexpr int NT = KC / 32;       // K-steps: FC1 24, FC2 48
  constexpr int ABY = 8192;         // A bf16 [128m][32k]
  constexpr int FBY = 16384;        // B fp32 [32k][128n] (staged linear)
  constexpr int BBY = 8192;         // B bf16 [128n][32k] (swizzled)
  constexpr int BUFB = ABY + FBY + BBY;  // 32 KB / buffer

  const int rb = blockIdx.x;
  if (rb >= *nrb) return;
  const int ge = rb_ge[rb];
  const int by = rb_by[rb];
  const int cnt = counts[ge];
  const int off = offsets[ge];
  const int nb = blockIdx.y;
  const int ks = (KS > 1) ? blockIdx.z : 0;
  const int kbase = ks * KC;
  const int tid = threadIdx.x;

  __shared__ __align__(16) unsigned char lds[2 * BUFB];

  // ---- A gld sources: slot q = tid + 256*i; row m = q>>2, chunk c = q&3.
  // Source chunk pre-swizzled (c ^ s(m)); LDS dest linear (q*16).
  const unsigned short* asrc[2];
#pragma unroll
  for (int i = 0; i < 2; ++i) {
    const int q = tid + 256 * i;
    const int m = q >> 2, c = q & 3;
    const int sc = c ^ ((m ^ (m >> 2)) & 3);
    int gr = by * 128 + m; if (gr >= cnt) gr = cnt - 1;
    const int row = GATHER ? slot_tok[off + gr] : (off + gr);
    asrc[i] = Abase + (size_t)row * K + kbase + sc * 8;
  }

  // ---- B fp32 gld sources: slot q = tid + 256*i; k = q>>5, col4 = q&31.
  // Fully linear/coalesced both sides.
  const float* fsrc[4];
#pragma unroll
  for (int i = 0; i < 4; ++i) {
    const int q = tid + 256 * i;
    fsrc[i] = W + (size_t)ge * K * NLD + (size_t)(kbase + (q >> 5)) * NLD
                + nb * 128 + (q & 31) * 4;
  }

  // ---- transpose geometry: thread owns col n = tid&127, k-half tk0.
  const int tn = tid & 127;
  const int tk0 = (tid >> 7) * 16;
  const int tsn = (tn ^ (tn >> 2)) & 3;

  // ---- fragment geometry
  const int w = tid >> 6, lane = tid & 63;
  const int wr = (w >> 1) * 64, wc = (w & 1) * 64;
  const int l15 = lane & 15, l4 = lane >> 4;
  int aoff[4], boff[4];
#pragma unroll
  for (int mf = 0; mf < 4; ++mf) {
    const int m = wr + mf * 16 + l15;
    aoff[mf] = m * 64 + ((l4 ^ ((m ^ (m >> 2)) & 3)) * 16);
  }
#pragma unroll
  for (int nf = 0; nf < 4; ++nf) {
    const int n = wc + nf * 16 + l15;
    boff[nf] = ABY + FBY + n * 64 + ((l4 ^ ((n ^ (n >> 2)) & 3)) * 16);
  }

  f32x4 acc[4][4];
#pragma unroll
  for (int mf = 0; mf < 4; ++mf)
#pragma unroll
    for (int nf = 0; nf < 4; ++nf)
      acc[mf][nf] = (f32x4){0.f, 0.f, 0.f, 0.f};

#define ISSUE(T, BASE) { \
    _Pragma("unroll") \
    for (int i = 0; i < 2; ++i) \
      gld_lds16(asrc[i] + (size_t)(T) * 32, (BASE) + (tid + 256 * i) * 16); \
    _Pragma("unroll") \
    for (int i = 0; i < 4; ++i) \
      gld_lds16(fsrc[i] + (size_t)(T) * 32 * NLD, (BASE) + ABY + (tid + 256 * i) * 16); }
#define TRANS(BASE) { \
    const float* fp = (const float*)((BASE) + ABY); \
    unsigned char* bb = (BASE) + ABY + FBY; \
    float fv[16]; \
    _Pragma("unroll") \
    for (int j = 0; j < 16; ++j) fv[j] = fp[(tk0 + j) * 128 + tn]; \
    _Pragma("unroll") \
    for (int jp = 0; jp < 8; ++jp) { \
      const unsigned wv = cvt_pk_bf16(fv[2 * jp], fv[2 * jp + 1]); \
      const int c = (tk0 * 2 + 4 * jp) >> 4; \
      *(unsigned*)(bb + tn * 64 + ((c ^ tsn) * 16) + ((4 * jp) & 15)) = wv; } }
#define COMPUTE(BASE) { bf16x8 afr[4], bfr[4]; _Pragma("unroll") \
    for (int mf = 0; mf < 4; ++mf) \
      afr[mf] = __builtin_bit_cast(bf16x8, *(const i32x4*)((BASE) + aoff[mf])); \
    _Pragma("unroll") \
    for (int nf = 0; nf < 4; ++nf) \
      bfr[nf] = __builtin_bit_cast(bf16x8, *(const i32x4*)((BASE) + boff[nf])); \
    _Pragma("unroll") \
    for (int mf = 0; mf < 4; ++mf) { _Pragma("unroll") \
      for (int nf = 0; nf < 4; ++nf) \
        acc[mf][nf] = __builtin_amdgcn_mfma_f32_16x16x32_bf16( \
            afr[mf], bfr[nf], acc[mf][nf], 0, 0, 0); } }

  // ---- prologue: tile 0 -> buf0
  ISSUE(0, lds);

  for (int t = 0; t < NT; ++t) {
    unsigned char* buf = lds + (t & 1) * BUFB;
    unsigned char* obuf = lds + ((t + 1) & 1) * BUFB;
    // only this wave's 6 gld_lds are in flight -> vmcnt(0) exact.
    asm volatile("s_waitcnt vmcnt(0)" ::: "memory");
    __builtin_amdgcn_s_barrier();
    asm volatile("" ::: "memory");
    if (t + 1 < NT) ISSUE(t + 1, obuf);  // flies across transpose+compute
    TRANS(buf);
    asm volatile("s_waitcnt lgkmcnt(0)" ::: "memory");
    __builtin_amdgcn_s_barrier();
    asm volatile("" ::: "memory");
    COMPUTE(buf);
  }
#undef ISSUE
#undef TRANS
#undef COMPUTE

  // ---- epilogue. C/D layout: col = lane&15, row = (lane>>4)*4 + j
#pragma unroll
  for (int mf = 0; mf < 4; ++mf) {
    const int rb2 = by * 128 + wr + mf * 16 + l4 * 4;
    if constexpr (EPI == 0) {
#pragma unroll
      for (int nf = 0; nf < 4; ++nf) {
        const int col = nb * 128 + wc + nf * 16 + l15;
        const float bv = bias[(size_t)ge * NLD + col];
#pragma unroll
        for (int j = 0; j < 4; ++j) {
          const int r = rb2 + j;
          if (r < cnt) {
            const float v = acc[mf][nf][j] + bv;
            const float gl = 0.5f * v * (1.f + erff(v * 0.70710678118654752f));
            Hout[(size_t)(off + r) * NLD + col] = f2bf(gl);
          }
        }
      }
    } else {
#pragma unroll
      for (int j = 0; j < 4; ++j) {
        const int r = rb2 + j;
        if (r < cnt) {
          const int slot = off + r;
          const float sw = slot_w[slot];
          const int tok = slot_tok[slot];
#pragma unroll
          for (int nf = 0; nf < 4; ++nf) {
            const int col = nb * 128 + wc + nf * 16 + l15;
            const float bv = (ks == 0) ? bias[(size_t)ge * NLD + col] : 0.f;
            atomicAdd(&Yout[(size_t)tok * DDIM + col], sw * (acc[mf][nf][j] + bv));
          }
        }
      }
    }
  }
}

// ---------------------------------------------------------------------------
// Workspace layout (bytes):
//   0    counts[32]     128  offsets[32]    256  cursor[32]   384 nrb
//   512  rb_ge[96]      896  rb_by[96]
//   2048 pair_e[8192]   34816 pair_w[8192]
//   67584 slot_tok[8192] 100352 slot_w[8192]
//   135168 xb[1024][768] bf16 (1.57 MB)
//   12715008 H[8192][3072] bf16 (50.3 MB)    (ws ~1.2 GB available)
// ---------------------------------------------------------------------------
extern "C" void kernel_launch(void* const* d_in, const int* in_sizes, int n_in,
                              void* d_out, int out_size, void* d_ws, size_t ws_size,
                              hipStream_t stream)
{
  const float* x  = (const float*)d_in[0];
  const float* Wg = (const float*)d_in[1];
  const float* bg = (const float*)d_in[2];
  const float* We = (const float*)d_in[3];
  const float* be = (const float*)d_in[4];
  const float* W1 = (const float*)d_in[5];
  const float* b1 = (const float*)d_in[6];
  const float* W2 = (const float*)d_in[7];
  const float* b2 = (const float*)d_in[8];
  float* y = (float*)d_out;

  char* ws = (char*)d_ws;
  int*   counts   = (int*)(ws + 0);
  int*   offsets  = (int*)(ws + 128);
  int*   cursor   = (int*)(ws + 256);
  int*   nrb      = (int*)(ws + 384);
  int*   rb_ge    = (int*)(ws + 512);
  int*   rb_by    = (int*)(ws + 896);
  int*   pair_e   = (int*)(ws + 2048);
  float* pair_w   = (float*)(ws + 34816);
  int*   slot_tok = (int*)(ws + 67584);
  float* slot_w   = (float*)(ws + 100352);
  unsigned short* xb = (unsigned short*)(ws + 135168);
  unsigned short* H  = (unsigned short*)(ws + 12715008);

  init_kernel<<<1, 256, 0, stream>>>((int*)ws);
  zero_y<<<NTOK * DDIM / 1024, 256, 0, stream>>>(y);
  x2bf<<<NTOK * DDIM / 4096, 256, 0, stream>>>(x, xb);
  gating_kernel<<<NTOK, 256, 0, stream>>>(x, Wg, bg, We, be, counts, pair_e, pair_w);
  scan_kernel<<<1, 64, 0, stream>>>(counts, offsets, rb_ge, rb_by, nrb);
  scatter_kernel<<<NPAIR / 256, 256, 0, stream>>>(pair_e, pair_w, offsets, cursor,
                                                  slot_tok, slot_w);

  // FC1: 96 row-blocks x 24 n-blocks; W1 fp32 direct; A gathered from xb.
  moe_gemm_gl<DDIM, MDIM, 0, 1, 1><<<dim3(MAXRB, MDIM / 128, 1), 256, 0, stream>>>(
      xb, W1, b1, counts, offsets, nullptr, slot_tok, rb_ge, rb_by, nrb, H, nullptr);
  // FC2: 96 row-blocks x 6 n-blocks x K-split 2; atomic into y.
  moe_gemm_gl<MDIM, DDIM, 1, 0, 2><<<dim3(MAXRB, DDIM / 128, 2), 256, 0, stream>>>(
      H, W2, b2, counts, offsets, slot_w, slot_tok, rb_ge, rb_by, nrb, nullptr, y);
}